// Round 3
// baseline (464.460 us; speedup 1.0000x reference)
//
#include <hip/hip_runtime.h>

// SparseInputLayer: inputs [B, ND*(1+NS)] fp32.
//  - cols [0,64): channel indices (float-encoded ints in [0,384))
//  - cols [64, 64+64*121): data rows x[b][j][s]
// out[b][c][s] = sum_{j: idx[b][j]==c} x[b][j][s], shape [2048,384,121,1] fp32.
//
// Round-3 structure: DECOUPLE stores from the mask dependence.
//   Rounds 0-2 showed time is invariant to per-element instruction count
//   (17->4 insts: no change) -> not VALU-bound. Every store was gated by
//   ds_read(mask) + data-dependent while-loop, which blocks store pipelining;
//   fill kernel (dependence-free stores) hits 6.2 TB/s vs our 2.3 TB/s.
// Pass 1: unconditional zero-fill of the block's 186KB output row --
//         dependence-free float4 store burst, identical pattern to the
//         proven-6.2TB/s fill kernel. (~85% of output is zero anyway.)
// Pass 2: overwrite ONLY the ~59 unique nonzero channels (LDS list built
//         during mask construction). 15% of the row, gather-summed.
// __syncthreads() between passes orders the same-block WAW (hipcc emits
// s_waitcnt vmcnt(0) before s_barrier, draining pass-1 stores).

#define BATCH 2048
#define N_DENSE 64
#define N_SAMPLES 121
#define N_CHANNELS 384
#define ROW_IN (N_DENSE * (1 + N_SAMPLES)) // 7808 floats per input row
#define ROW_OUT (N_CHANNELS * N_SAMPLES)   // 46464 floats per output row
#define NQUAD (ROW_OUT / 4)                // 11616 16B quads (exact: 46464=4*11616)
#define BLOCK 256
#define SPAD 128                           // samples padded to pow2 for pass-2 indexing

__global__ __launch_bounds__(BLOCK) void sparse_scatter_kernel(
    const float* __restrict__ in, float* __restrict__ out) {
  __shared__ unsigned long long mask[N_CHANNELS];
  __shared__ int list[N_DENSE]; // unique nonzero channels
  __shared__ int count;

  const int b = blockIdx.x;
  const int tid = threadIdx.x;

  // init per-channel membership masks + list counter
  for (int c = tid; c < N_CHANNELS; c += BLOCK) mask[c] = 0ull;
  if (tid == 0) count = 0;
  __syncthreads();

  // threads 0..63: set bit j in channel mask; first setter appends to list
  if (tid < N_DENSE) {
    const int c = (int)in[(size_t)b * ROW_IN + tid];
    const unsigned long long old = atomicOr(&mask[c], 1ull << tid);
    if (old == 0ull) {
      const int p = atomicAdd(&count, 1);
      list[p] = c;
    }
  }

  float* __restrict__ o = out + (size_t)b * ROW_OUT; // [384][121], 16B-aligned

  // ---- pass 1: unconditional zero-fill, dependence-free full-rate stores ----
  {
    const float4 z = make_float4(0.f, 0.f, 0.f, 0.f);
    float4* __restrict__ o4 = reinterpret_cast<float4*>(o);
    for (int i = tid; i < NQUAD; i += BLOCK) o4[i] = z; // 256B/wave, line-aligned
  }

  __syncthreads(); // drains vmcnt: pass-1 stores ordered before pass-2 overwrites

  // ---- pass 2: gather-sum and overwrite the ~59 nonzero channel rows ----
  const float* __restrict__ x = in + (size_t)b * ROW_IN + N_DENSE; // [64][121]
  const int K = count;
  for (int q = tid; q < K * SPAD; q += BLOCK) {
    const int ki = q >> 7;          // list index
    const int s = q & (SPAD - 1);   // sample
    if (s >= N_SAMPLES) continue;
    const int c = list[ki];
    unsigned long long m = mask[c]; // LDS broadcast within the channel group
    float sum = 0.f;
    while (m) {
      const int j = __builtin_ctzll(m);
      m &= m - 1;
      sum += x[j * N_SAMPLES + s]; // coalesced 484B per j across the group
    }
    o[c * N_SAMPLES + s] = sum;
  }
}

extern "C" void kernel_launch(void* const* d_in, const int* in_sizes, int n_in,
                              void* d_out, int out_size, void* d_ws, size_t ws_size,
                              hipStream_t stream) {
  const float* in = (const float*)d_in[0];
  float* out = (float*)d_out;
  sparse_scatter_kernel<<<BATCH, BLOCK, 0, stream>>>(in, out);
}

// Round 4
// 438.152 us; speedup vs baseline: 1.0600x; 1.0600x over previous
//
#include <hip/hip_runtime.h>

// SparseInputLayer: inputs [B, ND*(1+NS)] fp32.
//  - cols [0,64): channel indices (float-encoded ints in [0,384))
//  - cols [64, 64+64*121): data rows x[b][j][s]
// out[b][c][s] = sum_{j: idx[b][j]==c} x[b][j][s], shape [2048,384,121,1] fp32.
//
// Strategy: one block per batch. Build per-channel 64-bit "which j maps here"
// bitmask in LDS (scatter -> gather inversion), then stream the full output
// row [384*121] with one coalesced write per element (fuses zero-fill with
// the scatter-add; no global atomics, no memset pass).
//
// ROUND-4 NOTE (revert): rounds 1-3 tried wider stores (float4 quads),
// division-free channel slotting, and a decoupled fill+overwrite structure.
// All three REGRESSED (+19/+25/+28 us) with clean mechanisms (straddle-path
// divergence, idle lanes / broken wave coalescing, +59MB extra traffic).
// Cross-round analysis: this kernel's store stream is already at the
// achievable write roofline (~381MB out + 64MB in ~= 71us @ 6.3TB/s); the
// rest of dur_us is harness-fixed poison-fill (~245us, 1.49GB, visible in
// rocprof) + restore traffic. Keep: perfect 256B/wave store coalescing,
// zero divergence in the store loop, short dependence chains (~1.17 gather
// loads/element from the L1-resident 31KB x-slab).

#define BATCH 2048
#define N_DENSE 64
#define N_SAMPLES 121
#define N_CHANNELS 384
#define ROW_IN (N_DENSE * (1 + N_SAMPLES)) // 7808 floats per input row
#define ROW_OUT (N_CHANNELS * N_SAMPLES)   // 46464 floats per output row
#define BLOCK 256

__global__ __launch_bounds__(BLOCK) void sparse_scatter_kernel(
    const float* __restrict__ in, float* __restrict__ out) {
  __shared__ unsigned long long mask[N_CHANNELS];

  const int b = blockIdx.x;
  const int tid = threadIdx.x;

  // init per-channel membership masks
  for (int c = tid; c < N_CHANNELS; c += BLOCK) mask[c] = 0ull;
  __syncthreads();

  // threads 0..63 each own one dense slot j; set bit j in its channel's mask
  if (tid < N_DENSE) {
    const int c = (int)in[(size_t)b * ROW_IN + tid];
    atomicOr(&mask[c], 1ull << tid);
  }
  __syncthreads();

  const float* __restrict__ x = in + (size_t)b * ROW_IN + N_DENSE; // [64][121]
  float* __restrict__ o = out + (size_t)b * ROW_OUT;               // [384][121]

  // stream the output row: element e -> (c = e/121, s = e%121)
  for (int e = tid; e < ROW_OUT; e += BLOCK) {
    const int c = e / N_SAMPLES;
    const int s = e - c * N_SAMPLES;
    unsigned long long m = mask[c]; // LDS broadcast (same addr across the c-group)
    float sum = 0.0f;
    while (m) {
      const int j = __builtin_ctzll(m);
      m &= m - 1;
      sum += x[j * N_SAMPLES + s]; // per-batch x slab is 31 KB -> L1 resident
    }
    o[e] = sum; // exactly-once, fully coalesced store
  }
}

extern "C" void kernel_launch(void* const* d_in, const int* in_sizes, int n_in,
                              void* d_out, int out_size, void* d_ws, size_t ws_size,
                              hipStream_t stream) {
  const float* in = (const float*)d_in[0];
  float* out = (float*)d_out;
  sparse_scatter_kernel<<<BATCH, BLOCK, 0, stream>>>(in, out);
}